// Round 1
// baseline (223.086 us; speedup 1.0000x reference)
//
#include <hip/hip_runtime.h>
#include <math.h>

#define B  64
#define VL 256
#define TL 512
#define HD 512
#define KV 127   // (VL-1)/2
#define KT 255   // (TL-1)/2
#define EPSF 1e-8f

// workspace layout in 4-byte elements
#define WS_VN    0                      // B*VL floats
#define WS_TN    (B*VL)                 // B*TL floats
#define WS_RKEY  (WS_TN + B*TL)         // B*VL u32 (monotone float keys, rowmax)
#define WS_CKEY  (WS_RKEY + B*VL)       // B*TL u32 (colmax)
#define WS_SRC   (WS_CKEY + B*TL)       // B*768 i32 (gather source row per output row)
// total = 98304 + 49152 = 147456 elems = 576 KiB

__device__ __forceinline__ unsigned fkey(float f) {
    unsigned u = __float_as_uint(f);
    return (u & 0x80000000u) ? ~u : (u | 0x80000000u);  // order-preserving float->uint
}

__global__ void k_init(unsigned* __restrict__ keys) {
    int i = blockIdx.x * 256 + threadIdx.x;
    if (i < B * VL + B * TL) keys[i] = 0u;   // 0 == smallest key
}

// one wave per row, 4 rows per block
__global__ __launch_bounds__(256) void k_norms(const float* __restrict__ v,
                                               const float* __restrict__ t,
                                               float* __restrict__ vn,
                                               float* __restrict__ tn) {
    int row  = blockIdx.x * 4 + (threadIdx.x >> 6);
    int lane = threadIdx.x & 63;
    const float* p;
    float* o;
    if (row < B * VL) { p = v + (size_t)row * HD; o = vn + row; }
    else              { int rr = row - B * VL; p = t + (size_t)rr * HD; o = tn + rr; }
    float s = 0.f;
#pragma unroll
    for (int it = 0; it < 2; ++it) {
        float4 x = *(const float4*)(p + lane * 4 + it * 256);
        s += x.x * x.x + x.y * x.y + x.z * x.z + x.w * x.w;
    }
#pragma unroll
    for (int off = 32; off > 0; off >>= 1) s += __shfl_xor(s, off, 64);
    if (lane == 0) *o = sqrtf(s);
}

// per-batch GEMM tile (64x64, K=512) -> cosine sims -> row/col max via atomicMax on keys
__global__ __launch_bounds__(256) void k_simmax(const float* __restrict__ video,
                                                const float* __restrict__ text,
                                                const float* __restrict__ vn,
                                                const float* __restrict__ tn,
                                                unsigned* __restrict__ rkey,
                                                unsigned* __restrict__ ckey) {
    __shared__ __align__(16) float As[16][68];   // stride 68: 272B rows keep float4 16B-aligned
    __shared__ __align__(16) float Bs[16][68];
    __shared__ unsigned rowm[64], colm[64];

    int tid = threadIdx.x;
    int b   = blockIdx.x >> 5;
    int tl  = blockIdx.x & 31;
    int m0  = (tl >> 3) * 64;   // video tile base (VL/64 = 4 tiles)
    int n0  = (tl & 7) * 64;    // text tile base  (TL/64 = 8 tiles)

    const float* Vb = video + (size_t)b * VL * HD;
    const float* Tb = text  + (size_t)b * TL * HD;

    int tx = tid & 15, ty = tid >> 4;   // 16x16 threads, each 4x4 outputs
    int lr = tid >> 2;                  // staging: row 0..63
    int lk = (tid & 3) * 4;             // staging: k 0,4,8,12

    float acc[4][4] = {};

    for (int k0 = 0; k0 < HD; k0 += 16) {
        float4 av = *(const float4*)(Vb + (size_t)(m0 + lr) * HD + k0 + lk);
        float4 bv = *(const float4*)(Tb + (size_t)(n0 + lr) * HD + k0 + lk);
        __syncthreads();
        As[lk + 0][lr] = av.x; As[lk + 1][lr] = av.y; As[lk + 2][lr] = av.z; As[lk + 3][lr] = av.w;
        Bs[lk + 0][lr] = bv.x; Bs[lk + 1][lr] = bv.y; Bs[lk + 2][lr] = bv.z; Bs[lk + 3][lr] = bv.w;
        __syncthreads();
#pragma unroll
        for (int k = 0; k < 16; ++k) {
            float4 a4 = *(const float4*)&As[k][ty * 4];
            float4 b4 = *(const float4*)&Bs[k][tx * 4];
            float a_[4] = {a4.x, a4.y, a4.z, a4.w};
            float b_[4] = {b4.x, b4.y, b4.z, b4.w};
#pragma unroll
            for (int i = 0; i < 4; ++i)
#pragma unroll
                for (int j = 0; j < 4; ++j)
                    acc[i][j] = fmaf(a_[i], b_[j], acc[i][j]);
        }
    }

    float vnr[4], tnc[4];
#pragma unroll
    for (int i = 0; i < 4; ++i) vnr[i] = vn[b * VL + m0 + ty * 4 + i];
#pragma unroll
    for (int j = 0; j < 4; ++j) tnc[j] = tn[b * TL + n0 + tx * 4 + j];

    float rmax[4] = {-INFINITY, -INFINITY, -INFINITY, -INFINITY};
    float cmax[4] = {-INFINITY, -INFINITY, -INFINITY, -INFINITY};
#pragma unroll
    for (int i = 0; i < 4; ++i)
#pragma unroll
        for (int j = 0; j < 4; ++j) {
            float s = acc[i][j] / fmaxf(vnr[i] * tnc[j], EPSF);
            rmax[i] = fmaxf(rmax[i], s);
            cmax[j] = fmaxf(cmax[j], s);
        }

    if (tid < 64) { rowm[tid] = 0u; colm[tid] = 0u; }
    __syncthreads();
#pragma unroll
    for (int i = 0; i < 4; ++i) atomicMax(&rowm[ty * 4 + i], fkey(rmax[i]));
#pragma unroll
    for (int j = 0; j < 4; ++j) atomicMax(&colm[tx * 4 + j], fkey(cmax[j]));
    __syncthreads();
    if (tid < 64)       atomicMax(&rkey[b * VL + m0 + tid], rowm[tid]);
    else if (tid < 128) atomicMax(&ckey[b * TL + n0 + tid - 64], colm[tid - 64]);
}

// per-batch: pick top-KV rows / top-KT cols by max-sim (stable tie-break by index),
// emit gather source indices replicating _split_rows zero-pad/skip semantics
__global__ __launch_bounds__(512) void k_select(const unsigned* __restrict__ rkey,
                                                const unsigned* __restrict__ ckey,
                                                int* __restrict__ srcidx) {
    __shared__ unsigned rk[VL];
    __shared__ unsigned ck[TL];
    __shared__ unsigned char sv[VL];
    __shared__ unsigned char stx[TL];
    int b = blockIdx.x, tid = threadIdx.x;
    if (tid < VL) rk[tid] = rkey[b * VL + tid];
    ck[tid] = ckey[b * TL + tid];
    for (int i = tid; i < 768; i += 512) srcidx[b * 768 + i] = -1;
    __syncthreads();
    if (tid < VL) {
        unsigned me = rk[tid]; int c = 0;
        for (int j = 0; j < VL; ++j) c += (rk[j] > me) || (rk[j] == me && j < tid);
        sv[tid] = (c < KV) ? 1 : 0;
    }
    {
        unsigned me = ck[tid]; int c = 0;
        for (int j = 0; j < TL; ++j) c += (ck[j] > me) || (ck[j] == me && j < tid);
        stx[tid] = (c < KT) ? 1 : 0;
    }
    __syncthreads();
    if (tid < VL) {
        int ps = 0, pu = 0, m = 0;
        for (int j = 0; j < VL; ++j) {
            int s = sv[j];
            m += s;
            if (j < tid) { ps += s; pu += 1 - s; }
        }
        if (sv[tid]) srcidx[b * 768 + ps] = tid;                       // v_mut
        else {
            int pos = pu - (KV - m);                                    // skip first (KV-m) unselected
            if (pos >= 0 && pos < VL - KV) srcidx[b * 768 + 382 + pos] = tid;  // v_only
        }
    }
    {
        int ps = 0, pu = 0, m = 0;
        for (int j = 0; j < TL; ++j) {
            int s = stx[j];
            m += s;
            if (j < tid) { ps += s; pu += 1 - s; }
        }
        if (stx[tid]) srcidx[b * 768 + 127 + ps] = tid;                 // t_mut
        else {
            int pos = pu - (KT - m);
            if (pos >= 0 && pos < TL - KT) srcidx[b * 768 + 511 + pos] = tid;  // t_only
        }
    }
}

// one wave per output row; out element offset == row*HD since segments concatenate in row order
__global__ __launch_bounds__(256) void k_gather(const float* __restrict__ video,
                                                const float* __restrict__ text,
                                                const int* __restrict__ srcidx,
                                                float* __restrict__ out) {
    int row  = blockIdx.x * 4 + (threadIdx.x >> 6);
    int lane = threadIdx.x & 63;
    int b, base, L;
    const float* tens;
    const int S0 = B * KV, S1 = S0 + B * KT, S2 = S1 + B * (VL - KV);
    if (row < S0)      { b = row / KV;            base = 0   + row % KV;            tens = video; L = VL; }
    else if (row < S1) { int r = row - S0; b = r / KT;       base = 127 + r % KT;       tens = text;  L = TL; }
    else if (row < S2) { int r = row - S1; b = r / (VL - KV); base = 382 + r % (VL - KV); tens = video; L = VL; }
    else               { int r = row - S2; b = r / (TL - KT); base = 511 + r % (TL - KT); tens = text;  L = TL; }
    int s = srcidx[b * 768 + base];
    float* op = out + (size_t)row * HD;
    if (s >= 0) {
        const float* sp = tens + ((size_t)b * L + s) * HD;
#pragma unroll
        for (int it = 0; it < 2; ++it)
            *(float4*)(op + lane * 4 + it * 256) = *(const float4*)(sp + lane * 4 + it * 256);
    } else {
        float4 z = {0.f, 0.f, 0.f, 0.f};
#pragma unroll
        for (int it = 0; it < 2; ++it)
            *(float4*)(op + lane * 4 + it * 256) = z;
    }
}

extern "C" void kernel_launch(void* const* d_in, const int* in_sizes, int n_in,
                              void* d_out, int out_size, void* d_ws, size_t ws_size,
                              hipStream_t stream) {
    const float* video = (const float*)d_in[0];
    const float* text  = (const float*)d_in[1];
    float*    ws     = (float*)d_ws;
    float*    vn     = ws + WS_VN;
    float*    tn     = ws + WS_TN;
    unsigned* rkey   = (unsigned*)(ws + WS_RKEY);
    unsigned* ckey   = (unsigned*)(ws + WS_CKEY);
    int*      srcidx = (int*)(ws + WS_SRC);
    float*    out    = (float*)d_out;

    k_init  <<<(B * VL + B * TL + 255) / 256, 256, 0, stream>>>(rkey);  // rkey+ckey contiguous
    k_norms <<<(B * VL + B * TL) / 4,        256, 0, stream>>>(video, text, vn, tn);
    k_simmax<<<B * 32,                        256, 0, stream>>>(video, text, vn, tn, rkey, ckey);
    k_select<<<B,                             512, 0, stream>>>(rkey, ckey, srcidx);
    k_gather<<<(B * 768) / 4,                 256, 0, stream>>>(video, text, srcidx, out);
}

// Round 2
// 126.239 us; speedup vs baseline: 1.7672x; 1.7672x over previous
//
#include <hip/hip_runtime.h>
#include <math.h>

#define B_  64
#define VL 256
#define TL 512
#define HD 512
#define KV 127   // (VL-1)/2
#define KT 255   // (TL-1)/2
#define EPSF 1e-8f

typedef __attribute__((ext_vector_type(8))) short short8;
typedef __attribute__((ext_vector_type(4))) float f32x4;

// workspace layout in 4-byte elements
#define WS_RKEY  0                      // B_*VL u32 (monotone float keys, rowmax)
#define WS_CKEY  (B_*VL)                // B_*TL u32 (colmax)
#define WS_SRC   (WS_CKEY + B_*TL)     // B_*768 i32 gather sources

__device__ __forceinline__ unsigned fkey(float f) {
    unsigned u = __float_as_uint(f);
    return (u & 0x80000000u) ? ~u : (u | 0x80000000u);  // order-preserving float->uint
}

__device__ __forceinline__ ushort bfrn(float x) {
    unsigned u = __float_as_uint(x);
    return (ushort)((u + 0x7FFFu + ((u >> 16) & 1u)) >> 16);  // fp32 -> bf16 RNE
}

__device__ __forceinline__ void split2(float x, ushort& h, ushort& lo) {
    unsigned u  = __float_as_uint(x);
    unsigned hu = (u + 0x7FFFu + ((u >> 16) & 1u)) & 0xFFFF0000u;
    h  = (ushort)(hu >> 16);
    lo = bfrn(x - __uint_as_float(hu));   // exact residual, then RNE to bf16
}

__global__ void k_init(unsigned* __restrict__ keys) {
    int i = blockIdx.x * 256 + threadIdx.x;
    if (i < B_ * VL + B_ * TL) keys[i] = 0u;   // 0 == smallest key
}

// per-batch 128x128 tile, K=512: split-precision bf16 MFMA GEMM -> cosine -> row/col max
__global__ __launch_bounds__(256) void k_simmax(const float* __restrict__ video,
                                                const float* __restrict__ text,
                                                unsigned* __restrict__ rkey,
                                                unsigned* __restrict__ ckey) {
    __shared__ __align__(16) ushort Ah[128][40], Al[128][40];  // 32 k + 8 pad (80B rows, 16B-aligned)
    __shared__ __align__(16) ushort Bh[128][40], Bl[128][40];
    __shared__ float vns[128], tns[128];
    __shared__ unsigned rowm[128], colm[128];

    int tid = threadIdx.x;
    int b   = blockIdx.x >> 3;
    int tl  = blockIdx.x & 7;
    int m0  = (tl >> 2) * 128;   // video tile base (VL/128 = 2)
    int n0  = (tl & 3) * 128;    // text tile base  (TL/128 = 4)
    const float* Vb = video + (size_t)b * VL * HD;
    const float* Tb = text  + (size_t)b * TL * HD;

    if (tid < 128) rowm[tid] = 0u; else colm[tid - 128] = 0u;

    int l   = tid & 63, wid = tid >> 6;
    int wm  = (wid >> 1) * 64, wn = (wid & 1) * 64;   // wave quadrant
    int fr  = l & 15, g = l >> 4;

    int srow = tid >> 1;            // staging row 0..127
    int kc   = (tid & 1) * 16;      // staging k offset
    const float* ap = Vb + (size_t)(m0 + srow) * HD + kc;
    const float* bp = Tb + (size_t)(n0 + srow) * HD + kc;

    f32x4 acc[4][4];
#pragma unroll
    for (int i = 0; i < 4; ++i)
#pragma unroll
        for (int j = 0; j < 4; ++j) acc[i][j] = (f32x4){0.f, 0.f, 0.f, 0.f};

    float sa = 0.f, sb = 0.f;   // fused row sumsq (fp32 source values)

    for (int k0 = 0; k0 < HD; k0 += 32) {
        float4 av[4], bv[4];
#pragma unroll
        for (int c = 0; c < 4; ++c) {
            av[c] = *(const float4*)(ap + k0 + c * 4);
            bv[c] = *(const float4*)(bp + k0 + c * 4);
        }
        __syncthreads();   // prev iteration's frag reads complete before overwrite
#pragma unroll
        for (int c = 0; c < 4; ++c) {
            float4 x = av[c];
            sa = fmaf(x.x, x.x, fmaf(x.y, x.y, fmaf(x.z, x.z, fmaf(x.w, x.w, sa))));
            ushort4 h, lo;
            split2(x.x, h.x, lo.x); split2(x.y, h.y, lo.y);
            split2(x.z, h.z, lo.z); split2(x.w, h.w, lo.w);
            *(ushort4*)&Ah[srow][kc + c * 4] = h;
            *(ushort4*)&Al[srow][kc + c * 4] = lo;
            float4 y = bv[c];
            sb = fmaf(y.x, y.x, fmaf(y.y, y.y, fmaf(y.z, y.z, fmaf(y.w, y.w, sb))));
            split2(y.x, h.x, lo.x); split2(y.y, h.y, lo.y);
            split2(y.z, h.z, lo.z); split2(y.w, h.w, lo.w);
            *(ushort4*)&Bh[srow][kc + c * 4] = h;
            *(ushort4*)&Bl[srow][kc + c * 4] = lo;
        }
        __syncthreads();
        short8 fah[4], fal[4], fbh[4], fbl[4];
#pragma unroll
        for (int i = 0; i < 4; ++i) {
            fah[i] = *(const short8*)&Ah[wm + i * 16 + fr][g * 8];
            fal[i] = *(const short8*)&Al[wm + i * 16 + fr][g * 8];
            fbh[i] = *(const short8*)&Bh[wn + i * 16 + fr][g * 8];
            fbl[i] = *(const short8*)&Bl[wn + i * 16 + fr][g * 8];
        }
#pragma unroll
        for (int i = 0; i < 4; ++i)
#pragma unroll
            for (int j = 0; j < 4; ++j) {
                acc[i][j] = __builtin_amdgcn_mfma_f32_16x16x32_bf16(fah[i], fbh[j], acc[i][j], 0, 0, 0);
                acc[i][j] = __builtin_amdgcn_mfma_f32_16x16x32_bf16(fal[i], fbh[j], acc[i][j], 0, 0, 0);
                acc[i][j] = __builtin_amdgcn_mfma_f32_16x16x32_bf16(fah[i], fbl[j], acc[i][j], 0, 0, 0);
            }
    }

    // finish fused norms: pair (tid, tid^1) holds the two K-halves of row srow
    sa += __shfl_xor(sa, 1, 64);
    sb += __shfl_xor(sb, 1, 64);
    if ((tid & 1) == 0) { vns[srow] = sqrtf(sa); tns[srow] = sqrtf(sb); }
    __syncthreads();

    // epilogue: cosine + row/col max.  C layout: col = lane&15, row = (lane>>4)*4 + reg
    float vr[16], tc[4];
#pragma unroll
    for (int i = 0; i < 4; ++i)
#pragma unroll
        for (int r = 0; r < 4; ++r) vr[i * 4 + r] = vns[wm + i * 16 + g * 4 + r];
#pragma unroll
    for (int j = 0; j < 4; ++j) tc[j] = tns[wn + j * 16 + fr];

    float rmx[16], cmx[4];
#pragma unroll
    for (int i = 0; i < 16; ++i) rmx[i] = -INFINITY;
#pragma unroll
    for (int j = 0; j < 4; ++j) cmx[j] = -INFINITY;
#pragma unroll
    for (int i = 0; i < 4; ++i)
#pragma unroll
        for (int j = 0; j < 4; ++j)
#pragma unroll
            for (int r = 0; r < 4; ++r) {
                float s = acc[i][j][r] / fmaxf(vr[i * 4 + r] * tc[j], EPSF);
                rmx[i * 4 + r] = fmaxf(rmx[i * 4 + r], s);
                cmx[j]         = fmaxf(cmx[j], s);
            }
#pragma unroll
    for (int off = 1; off < 16; off <<= 1)
#pragma unroll
        for (int i = 0; i < 16; ++i) rmx[i] = fmaxf(rmx[i], __shfl_xor(rmx[i], off, 64));
#pragma unroll
    for (int off = 16; off < 64; off <<= 1)
#pragma unroll
        for (int j = 0; j < 4; ++j) cmx[j] = fmaxf(cmx[j], __shfl_xor(cmx[j], off, 64));
    if (fr == 0) {
#pragma unroll
        for (int i = 0; i < 4; ++i)
#pragma unroll
            for (int r = 0; r < 4; ++r)
                atomicMax(&rowm[wm + i * 16 + g * 4 + r], fkey(rmx[i * 4 + r]));
    }
    if (g == 0) {
#pragma unroll
        for (int j = 0; j < 4; ++j) atomicMax(&colm[wn + j * 16 + fr], fkey(cmx[j]));
    }
    __syncthreads();
    if (tid < 128) atomicMax(&rkey[b * VL + m0 + tid], rowm[tid]);
    else           atomicMax(&ckey[b * TL + n0 + (tid - 128)], colm[tid - 128]);
}

// per-batch: pick top-KV rows / top-KT cols by max-sim (stable tie-break by index),
// emit gather source indices replicating _split_rows zero-pad/skip semantics
__global__ __launch_bounds__(512) void k_select(const unsigned* __restrict__ rkey,
                                                const unsigned* __restrict__ ckey,
                                                int* __restrict__ srcidx) {
    __shared__ unsigned rk[VL];
    __shared__ unsigned ck[TL];
    __shared__ unsigned char sv[VL];
    __shared__ unsigned char stx[TL];
    int b = blockIdx.x, tid = threadIdx.x;
    if (tid < VL) rk[tid] = rkey[b * VL + tid];
    ck[tid] = ckey[b * TL + tid];
    for (int i = tid; i < 768; i += 512) srcidx[b * 768 + i] = -1;
    __syncthreads();
    if (tid < VL) {
        unsigned me = rk[tid]; int c = 0;
        for (int j = 0; j < VL; ++j) c += (rk[j] > me) || (rk[j] == me && j < tid);
        sv[tid] = (c < KV) ? 1 : 0;
    }
    {
        unsigned me = ck[tid]; int c = 0;
        for (int j = 0; j < TL; ++j) c += (ck[j] > me) || (ck[j] == me && j < tid);
        stx[tid] = (c < KT) ? 1 : 0;
    }
    __syncthreads();
    if (tid < VL) {
        int ps = 0, pu = 0, m = 0;
        for (int j = 0; j < VL; ++j) {
            int s = sv[j];
            m += s;
            if (j < tid) { ps += s; pu += 1 - s; }
        }
        if (sv[tid]) srcidx[b * 768 + ps] = tid;                       // v_mut
        else {
            int pos = pu - (KV - m);                                    // skip first (KV-m) unselected
            if (pos >= 0 && pos < VL - KV) srcidx[b * 768 + 382 + pos] = tid;  // v_only
        }
    }
    {
        int ps = 0, pu = 0, m = 0;
        for (int j = 0; j < TL; ++j) {
            int s = stx[j];
            m += s;
            if (j < tid) { ps += s; pu += 1 - s; }
        }
        if (stx[tid]) srcidx[b * 768 + 127 + ps] = tid;                 // t_mut
        else {
            int pos = pu - (KT - m);
            if (pos >= 0 && pos < TL - KT) srcidx[b * 768 + 511 + pos] = tid;  // t_only
        }
    }
}

// one wave per output row; out element offset == row*HD since segments concatenate in row order
__global__ __launch_bounds__(256) void k_gather(const float* __restrict__ video,
                                                const float* __restrict__ text,
                                                const int* __restrict__ srcidx,
                                                float* __restrict__ out) {
    int row  = blockIdx.x * 4 + (threadIdx.x >> 6);
    int lane = threadIdx.x & 63;
    int b, base, L;
    const float* tens;
    const int S0 = B_ * KV, S1 = S0 + B_ * KT, S2 = S1 + B_ * (VL - KV);
    if (row < S0)      { b = row / KV;            base = 0   + row % KV;            tens = video; L = VL; }
    else if (row < S1) { int r = row - S0; b = r / KT;       base = 127 + r % KT;       tens = text;  L = TL; }
    else if (row < S2) { int r = row - S1; b = r / (VL - KV); base = 382 + r % (VL - KV); tens = video; L = VL; }
    else               { int r = row - S2; b = r / (TL - KT); base = 511 + r % (TL - KT); tens = text;  L = TL; }
    int s = srcidx[b * 768 + base];
    float* op = out + (size_t)row * HD;
    if (s >= 0) {
        const float* sp = tens + ((size_t)b * L + s) * HD;
#pragma unroll
        for (int it = 0; it < 2; ++it)
            *(float4*)(op + lane * 4 + it * 256) = *(const float4*)(sp + lane * 4 + it * 256);
    } else {
        float4 z = {0.f, 0.f, 0.f, 0.f};
#pragma unroll
        for (int it = 0; it < 2; ++it)
            *(float4*)(op + lane * 4 + it * 256) = z;
    }
}

extern "C" void kernel_launch(void* const* d_in, const int* in_sizes, int n_in,
                              void* d_out, int out_size, void* d_ws, size_t ws_size,
                              hipStream_t stream) {
    const float* video = (const float*)d_in[0];
    const float* text  = (const float*)d_in[1];
    float*    ws     = (float*)d_ws;
    unsigned* rkey   = (unsigned*)(ws + WS_RKEY);
    unsigned* ckey   = (unsigned*)(ws + WS_CKEY);
    int*      srcidx = (int*)(ws + WS_SRC);
    float*    out    = (float*)d_out;

    k_init  <<<(B_ * VL + B_ * TL + 255) / 256, 256, 0, stream>>>(rkey);  // rkey+ckey contiguous
    k_simmax<<<B_ * 8,                           256, 0, stream>>>(video, text, rkey, ckey);
    k_select<<<B_,                               512, 0, stream>>>(rkey, ckey, srcidx);
    k_gather<<<(B_ * 768) / 4,                   256, 0, stream>>>(video, text, srcidx, out);
}

// Round 3
// 110.731 us; speedup vs baseline: 2.0147x; 1.1401x over previous
//
#include <hip/hip_runtime.h>
#include <math.h>

#define B_  64
#define VL 256
#define TL 512
#define HD 512
#define KV 127   // (VL-1)/2
#define KT 255   // (TL-1)/2
#define EPSF 1e-8f

typedef __attribute__((ext_vector_type(8))) short short8;
typedef __attribute__((ext_vector_type(8))) unsigned short ushort8;
typedef __attribute__((ext_vector_type(4))) float f32x4;

// workspace layout in 4-byte elements (no init needed: every slot written each call)
#define WS_ROWP  0                       // B_*4*VL u32 partial row maxes (per n-tile)
#define WS_COLP  (B_*4*VL)               // B_*2*TL u32 partial col maxes (per m-tile)
#define WS_SRC   (WS_COLP + B_*2*TL)     // B_*768 i32 gather sources

__device__ __forceinline__ unsigned fkey(float f) {
    unsigned u = __float_as_uint(f);
    return (u & 0x80000000u) ? ~u : (u | 0x80000000u);  // order-preserving float->uint
}

// truncation split: x = hi(bf16,trunc) + lo(bf16,RNE) ; dropped lo*lo term ~2^-16 rel
__device__ __forceinline__ void cvt_store(ushort* __restrict__ ph, ushort* __restrict__ pl,
                                          float4 x0, float4 x1, float& ss) {
    float xs[8] = {x0.x, x0.y, x0.z, x0.w, x1.x, x1.y, x1.z, x1.w};
    ushort8 h, lo;
#pragma unroll
    for (int k = 0; k < 8; ++k) {
        float x = xs[k];
        ss = fmaf(x, x, ss);
        unsigned hu = __float_as_uint(x) & 0xFFFF0000u;
        h[k] = (ushort)(hu >> 16);
        float r = x - __uint_as_float(hu);
        unsigned ur = __float_as_uint(r);
        lo[k] = (ushort)((ur + 0x7FFFu + ((ur >> 16) & 1u)) >> 16);
    }
    *(ushort8*)ph = h;
    *(ushort8*)pl = lo;
}

// per-batch 128x128 tile, K=512, 8 waves: split-bf16 MFMA, dbuf LDS, swizzled, async-stage
__global__ __launch_bounds__(512, 4) void k_simmax(const float* __restrict__ video,
                                                   const float* __restrict__ text,
                                                   unsigned* __restrict__ rowp,
                                                   unsigned* __restrict__ colp) {
    // planes: 0=Ah 1=Al 2=Bh 3=Bl ; 128 rows x 32 k bf16, 64B rows, chunk-XOR swizzle
    __shared__ __align__(16) ushort planes[2][4][4096];
    __shared__ float vns_s[128], tns_s[128];
    __shared__ unsigned rowm[128], colm[128];

    int bb = blockIdx.x;
    // XCD swizzle: batch's 8 tiles share one XCD (hw xcd = blockIdx % 8)
    int z = bb & 7, y = (bb >> 3) & 7, x = bb >> 6;
    int b = z * 8 + x;
    int mt = y >> 2, nt = y & 3;
    int m0 = mt * 128, n0 = nt * 128;

    const float* Vb = video + (size_t)b * VL * HD;
    const float* Tb = text  + (size_t)b * TL * HD;

    int tid = threadIdx.x;
    int l = tid & 63, wid = tid >> 6;
    int fr = l & 15, g = l >> 4;
    int wm = (wid >> 1) * 32, wn = (wid & 1) * 64;   // wave tile: 32 x 64

    int srow = tid >> 2;            // staging row 0..127
    int c    = tid & 3;             // staging data k-chunk (8 elems)
    unsigned widx = srow * 32 + ((c ^ ((srow >> 1) & 3)) * 8);

    const float* aptr = Vb + (size_t)(m0 + srow) * HD + c * 8;
    const float* bptr = Tb + (size_t)(n0 + srow) * HD + c * 8;

    f32x4 acc[2][4];
#pragma unroll
    for (int i = 0; i < 2; ++i)
#pragma unroll
        for (int j = 0; j < 4; ++j) acc[i][j] = (f32x4){0.f, 0.f, 0.f, 0.f};

    float sa = 0.f, sb = 0.f;

    // prologue: stage step 0, prefetch step 1
    float4 ra0 = *(const float4*)(aptr);
    float4 ra1 = *(const float4*)(aptr + 4);
    float4 rb0 = *(const float4*)(bptr);
    float4 rb1 = *(const float4*)(bptr + 4);
    cvt_store(&planes[0][0][widx], &planes[0][1][widx], ra0, ra1, sa);
    cvt_store(&planes[0][2][widx], &planes[0][3][widx], rb0, rb1, sb);
    ra0 = *(const float4*)(aptr + 32); ra1 = *(const float4*)(aptr + 36);
    rb0 = *(const float4*)(bptr + 32); rb1 = *(const float4*)(bptr + 36);
    __syncthreads();

    for (int t = 0; t < 16; ++t) {
        int cur = t & 1, nxt = cur ^ 1;
        // frag reads first (ds_read latency hides under the conversion VALU below)
        short8 fah[2], fal[2], fbh[4], fbl[4];
#pragma unroll
        for (int i = 0; i < 2; ++i) {
            int row = wm + i * 16 + fr;
            unsigned ridx = row * 32 + ((g ^ ((row >> 1) & 3)) * 8);
            fah[i] = *(const short8*)&planes[cur][0][ridx];
            fal[i] = *(const short8*)&planes[cur][1][ridx];
        }
#pragma unroll
        for (int j = 0; j < 4; ++j) {
            int row = wn + j * 16 + fr;
            unsigned ridx = row * 32 + ((g ^ ((row >> 1) & 3)) * 8);
            fbh[j] = *(const short8*)&planes[cur][2][ridx];
            fbl[j] = *(const short8*)&planes[cur][3][ridx];
        }
        if (t < 15) {
            cvt_store(&planes[nxt][0][widx], &planes[nxt][1][widx], ra0, ra1, sa);
            cvt_store(&planes[nxt][2][widx], &planes[nxt][3][widx], rb0, rb1, sb);
            if (t < 14) {
                const float* ap = aptr + (t + 2) * 32;
                const float* bp = bptr + (t + 2) * 32;
                ra0 = *(const float4*)ap; ra1 = *(const float4*)(ap + 4);
                rb0 = *(const float4*)bp; rb1 = *(const float4*)(bp + 4);
            }
        }
#pragma unroll
        for (int j = 0; j < 4; ++j)
#pragma unroll
            for (int i = 0; i < 2; ++i) {
                acc[i][j] = __builtin_amdgcn_mfma_f32_16x16x32_bf16(fah[i], fbh[j], acc[i][j], 0, 0, 0);
                acc[i][j] = __builtin_amdgcn_mfma_f32_16x16x32_bf16(fal[i], fbh[j], acc[i][j], 0, 0, 0);
                acc[i][j] = __builtin_amdgcn_mfma_f32_16x16x32_bf16(fah[i], fbl[j], acc[i][j], 0, 0, 0);
            }
        __syncthreads();
    }

    // finish fused norms: row srow's 32-k slices live in lanes tid, tid^1, tid^2
    sa += __shfl_xor(sa, 1, 64); sa += __shfl_xor(sa, 2, 64);
    sb += __shfl_xor(sb, 1, 64); sb += __shfl_xor(sb, 2, 64);
    if ((tid & 3) == 0) { vns_s[srow] = sqrtf(sa); tns_s[srow] = sqrtf(sb); }
    if (tid < 128) rowm[tid] = 0u;
    else if (tid < 256) colm[tid - 128] = 0u;
    __syncthreads();

    // epilogue: cosine + row/col max.  C layout: col = lane&15 (N), row = g*4+reg (M)
    float vr[8], tc[4];
#pragma unroll
    for (int i = 0; i < 2; ++i)
#pragma unroll
        for (int r = 0; r < 4; ++r) vr[i * 4 + r] = vns_s[wm + i * 16 + g * 4 + r];
#pragma unroll
    for (int j = 0; j < 4; ++j) tc[j] = tns_s[wn + j * 16 + fr];

    float rmx[8], cmx[4];
#pragma unroll
    for (int i = 0; i < 8; ++i) rmx[i] = -INFINITY;
#pragma unroll
    for (int j = 0; j < 4; ++j) cmx[j] = -INFINITY;
#pragma unroll
    for (int i = 0; i < 2; ++i)
#pragma unroll
        for (int j = 0; j < 4; ++j)
#pragma unroll
            for (int r = 0; r < 4; ++r) {
                float s = acc[i][j][r] / fmaxf(vr[i * 4 + r] * tc[j], EPSF);
                rmx[i * 4 + r] = fmaxf(rmx[i * 4 + r], s);
                cmx[j]         = fmaxf(cmx[j], s);
            }
#pragma unroll
    for (int off = 1; off < 16; off <<= 1)
#pragma unroll
        for (int i = 0; i < 8; ++i) rmx[i] = fmaxf(rmx[i], __shfl_xor(rmx[i], off, 64));
#pragma unroll
    for (int off = 16; off < 64; off <<= 1)
#pragma unroll
        for (int j = 0; j < 4; ++j) cmx[j] = fmaxf(cmx[j], __shfl_xor(cmx[j], off, 64));
    if (fr == 0) {
#pragma unroll
        for (int i = 0; i < 2; ++i)
#pragma unroll
            for (int r = 0; r < 4; ++r)
                atomicMax(&rowm[wm + i * 16 + g * 4 + r], fkey(rmx[i * 4 + r]));
    }
    if (g == 0) {
#pragma unroll
        for (int j = 0; j < 4; ++j) atomicMax(&colm[wn + j * 16 + fr], fkey(cmx[j]));
    }
    __syncthreads();
    if (tid < 128)      rowp[(b * 4 + nt) * VL + m0 + tid] = rowm[tid];
    else if (tid < 256) colp[(b * 2 + mt) * TL + n0 + (tid - 128)] = colm[tid - 128];
}

// per-batch: combine partials, pick top-KV rows / top-KT cols (stable tie-break by index),
// emit gather source indices replicating _split_rows zero-pad/skip semantics
__global__ __launch_bounds__(512) void k_select(const unsigned* __restrict__ rowp,
                                                const unsigned* __restrict__ colp,
                                                int* __restrict__ srcidx) {
    __shared__ unsigned rk[VL];
    __shared__ unsigned ck[TL];
    __shared__ unsigned char sv[VL];
    __shared__ unsigned char stx[TL];
    int b = blockIdx.x, tid = threadIdx.x;
    if (tid < VL) {
        unsigned m = rowp[(b * 4 + 0) * VL + tid];
        m = max(m, rowp[(b * 4 + 1) * VL + tid]);
        m = max(m, rowp[(b * 4 + 2) * VL + tid]);
        m = max(m, rowp[(b * 4 + 3) * VL + tid]);
        rk[tid] = m;
    }
    ck[tid] = max(colp[(b * 2 + 0) * TL + tid], colp[(b * 2 + 1) * TL + tid]);
    for (int i = tid; i < 768; i += 512) srcidx[b * 768 + i] = -1;
    __syncthreads();
    if (tid < VL) {
        unsigned me = rk[tid]; int cnt = 0;
        for (int j = 0; j < VL; ++j) cnt += (rk[j] > me) || (rk[j] == me && j < tid);
        sv[tid] = (cnt < KV) ? 1 : 0;
    }
    {
        unsigned me = ck[tid]; int cnt = 0;
        for (int j = 0; j < TL; ++j) cnt += (ck[j] > me) || (ck[j] == me && j < tid);
        stx[tid] = (cnt < KT) ? 1 : 0;
    }
    __syncthreads();
    if (tid < VL) {
        int ps = 0, pu = 0, m = 0;
        for (int j = 0; j < VL; ++j) {
            int s = sv[j];
            m += s;
            if (j < tid) { ps += s; pu += 1 - s; }
        }
        if (sv[tid]) srcidx[b * 768 + ps] = tid;                       // v_mut
        else {
            int pos = pu - (KV - m);                                    // skip first (KV-m) unselected
            if (pos >= 0 && pos < VL - KV) srcidx[b * 768 + 382 + pos] = tid;  // v_only
        }
    }
    {
        int ps = 0, pu = 0, m = 0;
        for (int j = 0; j < TL; ++j) {
            int s = stx[j];
            m += s;
            if (j < tid) { ps += s; pu += 1 - s; }
        }
        if (stx[tid]) srcidx[b * 768 + 127 + ps] = tid;                 // t_mut
        else {
            int pos = pu - (KT - m);
            if (pos >= 0 && pos < TL - KT) srcidx[b * 768 + 511 + pos] = tid;  // t_only
        }
    }
}

// one wave per output row; out element offset == row*HD since segments concatenate in row order
__global__ __launch_bounds__(256) void k_gather(const float* __restrict__ video,
                                                const float* __restrict__ text,
                                                const int* __restrict__ srcidx,
                                                float* __restrict__ out) {
    int row  = blockIdx.x * 4 + (threadIdx.x >> 6);
    int lane = threadIdx.x & 63;
    int b, base, L;
    const float* tens;
    const int S0 = B_ * KV, S1 = S0 + B_ * KT, S2 = S1 + B_ * (VL - KV);
    if (row < S0)      { b = row / KV;            base = 0   + row % KV;            tens = video; L = VL; }
    else if (row < S1) { int r = row - S0; b = r / KT;       base = 127 + r % KT;       tens = text;  L = TL; }
    else if (row < S2) { int r = row - S1; b = r / (VL - KV); base = 382 + r % (VL - KV); tens = video; L = VL; }
    else               { int r = row - S2; b = r / (TL - KT); base = 511 + r % (TL - KT); tens = text;  L = TL; }
    int s = srcidx[b * 768 + base];
    float* op = out + (size_t)row * HD;
    if (s >= 0) {
        const float* sp = tens + ((size_t)b * L + s) * HD;
#pragma unroll
        for (int it = 0; it < 2; ++it)
            *(float4*)(op + lane * 4 + it * 256) = *(const float4*)(sp + lane * 4 + it * 256);
    } else {
        float4 zv = {0.f, 0.f, 0.f, 0.f};
#pragma unroll
        for (int it = 0; it < 2; ++it)
            *(float4*)(op + lane * 4 + it * 256) = zv;
    }
}

extern "C" void kernel_launch(void* const* d_in, const int* in_sizes, int n_in,
                              void* d_out, int out_size, void* d_ws, size_t ws_size,
                              hipStream_t stream) {
    const float* video = (const float*)d_in[0];
    const float* text  = (const float*)d_in[1];
    float*    ws     = (float*)d_ws;
    unsigned* rowp   = (unsigned*)(ws + WS_ROWP);
    unsigned* colp   = (unsigned*)(ws + WS_COLP);
    int*      srcidx = (int*)(ws + WS_SRC);
    float*    out    = (float*)d_out;

    k_simmax<<<B_ * 8,          512, 0, stream>>>(video, text, rowp, colp);
    k_select<<<B_,              512, 0, stream>>>(rowp, colp, srcidx);
    k_gather<<<(B_ * 768) / 4,  256, 0, stream>>>(video, text, srcidx, out);
}

// Round 4
// 109.211 us; speedup vs baseline: 2.0427x; 1.0139x over previous
//
#include <hip/hip_runtime.h>
#include <math.h>

#define B_  64
#define VL 256
#define TL 512
#define HD 512
#define KV 127   // (VL-1)/2
#define KT 255   // (TL-1)/2
#define EPSF 1e-8f

typedef __attribute__((ext_vector_type(8))) short short8;
typedef __attribute__((ext_vector_type(4))) float f32x4;

// workspace layout in 4-byte elements (no init needed: every slot written each call)
#define WS_ROWP  0                       // B_*4*VL u32 partial row maxes (per n-tile)
#define WS_COLP  (B_*4*VL)               // B_*2*TL u32 partial col maxes (per m-tile)
#define WS_SRC   (WS_COLP + B_*2*TL)     // B_*768 i32 gather sources

__device__ __forceinline__ unsigned fkey(float f) {
    unsigned u = __float_as_uint(f);
    return (u & 0x80000000u) ? ~u : (u | 0x80000000u);  // order-preserving float->uint
}

__device__ __forceinline__ unsigned cvt_pk_bf16(float a, float b) {
    unsigned r;
    asm("v_cvt_pk_bf16_f32 %0, %1, %2" : "=v"(r) : "v"(a), "v"(b));
    return r;   // {bf16(a) lo, bf16(b) hi}, RNE
}

// trunc-split pair-packed: x = hi(trunc bf16) + lo(RNE bf16); ~4 VALU ops/element
__device__ __forceinline__ void cvt_store8(unsigned* __restrict__ ph, unsigned* __restrict__ pl,
                                           float4 x0, float4 x1, float& ss) {
    float xs[8] = {x0.x, x0.y, x0.z, x0.w, x1.x, x1.y, x1.z, x1.w};
    unsigned hh[4], ll[4];
#pragma unroll
    for (int k = 0; k < 4; ++k) {
        float a = xs[2 * k], b = xs[2 * k + 1];
        ss = fmaf(a, a, ss);
        ss = fmaf(b, b, ss);
        unsigned ua = __float_as_uint(a) & 0xFFFF0000u;
        unsigned ub = __float_as_uint(b) & 0xFFFF0000u;
        hh[k] = __builtin_amdgcn_perm(ub, ua, 0x07060302u);   // {a.hi16, b.hi16}
        ll[k] = cvt_pk_bf16(a - __uint_as_float(ua), b - __uint_as_float(ub));
    }
    *(uint4*)ph = (uint4){hh[0], hh[1], hh[2], hh[3]};
    *(uint4*)pl = (uint4){ll[0], ll[1], ll[2], ll[3]};
}

// per-batch 128x128 tile, K=512, 8 waves: split-bf16 MFMA, dbuf LDS, swizzled, async-stage
__global__ __launch_bounds__(512, 4) void k_simmax(const float* __restrict__ video,
                                                   const float* __restrict__ text,
                                                   unsigned* __restrict__ rowp,
                                                   unsigned* __restrict__ colp) {
    // planes: 0=Ah 1=Al 2=Bh 3=Bl ; 128 rows x 32 k bf16 = 16 uints/row, chunk-XOR swizzle
    __shared__ __align__(16) unsigned planes[2][4][2048];
    __shared__ float vns_s[128], tns_s[128];
    __shared__ unsigned rowm[128], colm[128];

    int bb = blockIdx.x;
    // XCD swizzle: batch's 8 tiles share one XCD (hw xcd = blockIdx % 8)
    int z = bb & 7, y = (bb >> 3) & 7, x = bb >> 6;
    int b = z * 8 + x;
    int mt = y >> 2, nt = y & 3;
    int m0 = mt * 128, n0 = nt * 128;

    const float* Vb = video + (size_t)b * VL * HD;
    const float* Tb = text  + (size_t)b * TL * HD;

    int tid = threadIdx.x;
    int l = tid & 63, wid = tid >> 6;
    int fr = l & 15, g = l >> 4;
    int wm = (wid >> 1) * 32, wn = (wid & 1) * 64;   // wave tile: 32 x 64

    int srow = tid >> 2;            // staging row 0..127
    int c    = tid & 3;             // staging data k-chunk (8 elems = 4 uints)
    unsigned widx = srow * 16 + (c ^ ((srow >> 1) & 3)) * 4;

    const float* aptr = Vb + (size_t)(m0 + srow) * HD + c * 8;
    const float* bptr = Tb + (size_t)(n0 + srow) * HD + c * 8;

    f32x4 acc[2][4];
#pragma unroll
    for (int i = 0; i < 2; ++i)
#pragma unroll
        for (int j = 0; j < 4; ++j) acc[i][j] = (f32x4){0.f, 0.f, 0.f, 0.f};

    float sa = 0.f, sb = 0.f;

    // prologue: stage step 0, prefetch step 1
    float4 ra0 = *(const float4*)(aptr);
    float4 ra1 = *(const float4*)(aptr + 4);
    float4 rb0 = *(const float4*)(bptr);
    float4 rb1 = *(const float4*)(bptr + 4);
    cvt_store8(&planes[0][0][widx], &planes[0][1][widx], ra0, ra1, sa);
    cvt_store8(&planes[0][2][widx], &planes[0][3][widx], rb0, rb1, sb);
    ra0 = *(const float4*)(aptr + 32); ra1 = *(const float4*)(aptr + 36);
    rb0 = *(const float4*)(bptr + 32); rb1 = *(const float4*)(bptr + 36);
    __syncthreads();

    for (int t = 0; t < 16; ++t) {
        int cur = t & 1, nxt = cur ^ 1;
        // frag reads first (ds_read latency hides under the conversion VALU below)
        short8 fah[2], fal[2], fbh[4], fbl[4];
#pragma unroll
        for (int i = 0; i < 2; ++i) {
            int row = wm + i * 16 + fr;
            unsigned ridx = row * 16 + (g ^ ((row >> 1) & 3)) * 4;
            fah[i] = *(const short8*)&planes[cur][0][ridx];
            fal[i] = *(const short8*)&planes[cur][1][ridx];
        }
#pragma unroll
        for (int j = 0; j < 4; ++j) {
            int row = wn + j * 16 + fr;
            unsigned ridx = row * 16 + (g ^ ((row >> 1) & 3)) * 4;
            fbh[j] = *(const short8*)&planes[cur][2][ridx];
            fbl[j] = *(const short8*)&planes[cur][3][ridx];
        }
        if (t < 15) {
            cvt_store8(&planes[nxt][0][widx], &planes[nxt][1][widx], ra0, ra1, sa);
            cvt_store8(&planes[nxt][2][widx], &planes[nxt][3][widx], rb0, rb1, sb);
            if (t < 14) {
                const float* ap = aptr + (t + 2) * 32;
                const float* bp = bptr + (t + 2) * 32;
                ra0 = *(const float4*)ap; ra1 = *(const float4*)(ap + 4);
                rb0 = *(const float4*)bp; rb1 = *(const float4*)(bp + 4);
            }
        }
        // 3 passes: 8 independent MFMAs between reuses of each acc (hide MFMA latency)
#pragma unroll
        for (int j = 0; j < 4; ++j)
#pragma unroll
            for (int i = 0; i < 2; ++i)
                acc[i][j] = __builtin_amdgcn_mfma_f32_16x16x32_bf16(fah[i], fbh[j], acc[i][j], 0, 0, 0);
#pragma unroll
        for (int j = 0; j < 4; ++j)
#pragma unroll
            for (int i = 0; i < 2; ++i)
                acc[i][j] = __builtin_amdgcn_mfma_f32_16x16x32_bf16(fal[i], fbh[j], acc[i][j], 0, 0, 0);
#pragma unroll
        for (int j = 0; j < 4; ++j)
#pragma unroll
            for (int i = 0; i < 2; ++i)
                acc[i][j] = __builtin_amdgcn_mfma_f32_16x16x32_bf16(fah[i], fbl[j], acc[i][j], 0, 0, 0);
        __syncthreads();
    }

    // finish fused norms: row srow's 32-k slices live in lanes tid, tid^1, tid^2
    sa += __shfl_xor(sa, 1, 64); sa += __shfl_xor(sa, 2, 64);
    sb += __shfl_xor(sb, 1, 64); sb += __shfl_xor(sb, 2, 64);
    if ((tid & 3) == 0) { vns_s[srow] = sqrtf(sa); tns_s[srow] = sqrtf(sb); }
    if (tid < 128) rowm[tid] = 0u;
    else if (tid < 256) colm[tid - 128] = 0u;
    __syncthreads();

    // epilogue: cosine + row/col max.  C layout: col = lane&15 (N), row = g*4+reg (M)
    float vr[8], tc[4];
#pragma unroll
    for (int i = 0; i < 2; ++i)
#pragma unroll
        for (int r = 0; r < 4; ++r) vr[i * 4 + r] = vns_s[wm + i * 16 + g * 4 + r];
#pragma unroll
    for (int j = 0; j < 4; ++j) tc[j] = tns_s[wn + j * 16 + fr];

    float rmx[8], cmx[4];
#pragma unroll
    for (int i = 0; i < 8; ++i) rmx[i] = -INFINITY;
#pragma unroll
    for (int j = 0; j < 4; ++j) cmx[j] = -INFINITY;
#pragma unroll
    for (int i = 0; i < 2; ++i)
#pragma unroll
        for (int j = 0; j < 4; ++j)
#pragma unroll
            for (int r = 0; r < 4; ++r) {
                float s = acc[i][j][r] / fmaxf(vr[i * 4 + r] * tc[j], EPSF);
                rmx[i * 4 + r] = fmaxf(rmx[i * 4 + r], s);
                cmx[j]         = fmaxf(cmx[j], s);
            }
#pragma unroll
    for (int off = 1; off < 16; off <<= 1)
#pragma unroll
        for (int i = 0; i < 8; ++i) rmx[i] = fmaxf(rmx[i], __shfl_xor(rmx[i], off, 64));
#pragma unroll
    for (int off = 16; off < 64; off <<= 1)
#pragma unroll
        for (int j = 0; j < 4; ++j) cmx[j] = fmaxf(cmx[j], __shfl_xor(cmx[j], off, 64));
    if (fr == 0) {
#pragma unroll
        for (int i = 0; i < 2; ++i)
#pragma unroll
            for (int r = 0; r < 4; ++r)
                atomicMax(&rowm[wm + i * 16 + g * 4 + r], fkey(rmx[i * 4 + r]));
    }
    if (g == 0) {
#pragma unroll
        for (int j = 0; j < 4; ++j) atomicMax(&colm[wn + j * 16 + fr], fkey(cmx[j]));
    }
    __syncthreads();
    if (tid < 128)      rowp[(b * 4 + nt) * VL + m0 + tid] = rowm[tid];
    else if (tid < 256) colp[(b * 2 + mt) * TL + n0 + (tid - 128)] = colm[tid - 128];
}

// per-batch: combine partials, pick top-KV rows / top-KT cols (stable tie-break by index),
// emit gather source indices replicating _split_rows zero-pad/skip semantics
__global__ __launch_bounds__(512) void k_select(const unsigned* __restrict__ rowp,
                                                const unsigned* __restrict__ colp,
                                                int* __restrict__ srcidx) {
    __shared__ unsigned rk[VL];
    __shared__ unsigned ck[TL];
    __shared__ unsigned char sv[VL];
    __shared__ unsigned char stx[TL];
    int b = blockIdx.x, tid = threadIdx.x;
    if (tid < VL) {
        unsigned m = rowp[(b * 4 + 0) * VL + tid];
        m = max(m, rowp[(b * 4 + 1) * VL + tid]);
        m = max(m, rowp[(b * 4 + 2) * VL + tid]);
        m = max(m, rowp[(b * 4 + 3) * VL + tid]);
        rk[tid] = m;
    }
    ck[tid] = max(colp[(b * 2 + 0) * TL + tid], colp[(b * 2 + 1) * TL + tid]);
    for (int i = tid; i < 768; i += 512) srcidx[b * 768 + i] = -1;
    __syncthreads();
    if (tid < VL) {
        unsigned me = rk[tid]; int cnt = 0;
        for (int j = 0; j < VL; ++j) cnt += (rk[j] > me) || (rk[j] == me && j < tid);
        sv[tid] = (cnt < KV) ? 1 : 0;
    }
    {
        unsigned me = ck[tid]; int cnt = 0;
        for (int j = 0; j < TL; ++j) cnt += (ck[j] > me) || (ck[j] == me && j < tid);
        stx[tid] = (cnt < KT) ? 1 : 0;
    }
    __syncthreads();
    if (tid < VL) {
        int ps = 0, pu = 0, m = 0;
        for (int j = 0; j < VL; ++j) {
            int s = sv[j];
            m += s;
            if (j < tid) { ps += s; pu += 1 - s; }
        }
        if (sv[tid]) srcidx[b * 768 + ps] = tid;                       // v_mut
        else {
            int pos = pu - (KV - m);                                    // skip first (KV-m) unselected
            if (pos >= 0 && pos < VL - KV) srcidx[b * 768 + 382 + pos] = tid;  // v_only
        }
    }
    {
        int ps = 0, pu = 0, m = 0;
        for (int j = 0; j < TL; ++j) {
            int s = stx[j];
            m += s;
            if (j < tid) { ps += s; pu += 1 - s; }
        }
        if (stx[tid]) srcidx[b * 768 + 127 + ps] = tid;                 // t_mut
        else {
            int pos = pu - (KT - m);
            if (pos >= 0 && pos < TL - KT) srcidx[b * 768 + 511 + pos] = tid;  // t_only
        }
    }
}

// one wave per output row; out element offset == row*HD since segments concatenate in row order
__global__ __launch_bounds__(256) void k_gather(const float* __restrict__ video,
                                                const float* __restrict__ text,
                                                const int* __restrict__ srcidx,
                                                float* __restrict__ out) {
    int row  = blockIdx.x * 4 + (threadIdx.x >> 6);
    int lane = threadIdx.x & 63;
    int b, base, L;
    const float* tens;
    const int S0 = B_ * KV, S1 = S0 + B_ * KT, S2 = S1 + B_ * (VL - KV);
    if (row < S0)      { b = row / KV;            base = 0   + row % KV;            tens = video; L = VL; }
    else if (row < S1) { int r = row - S0; b = r / KT;       base = 127 + r % KT;       tens = text;  L = TL; }
    else if (row < S2) { int r = row - S1; b = r / (VL - KV); base = 382 + r % (VL - KV); tens = video; L = VL; }
    else               { int r = row - S2; b = r / (TL - KT); base = 511 + r % (TL - KT); tens = text;  L = TL; }
    int s = srcidx[b * 768 + base];
    float* op = out + (size_t)row * HD;
    if (s >= 0) {
        const float* sp = tens + ((size_t)b * L + s) * HD;
#pragma unroll
        for (int it = 0; it < 2; ++it)
            *(float4*)(op + lane * 4 + it * 256) = *(const float4*)(sp + lane * 4 + it * 256);
    } else {
        float4 zv = {0.f, 0.f, 0.f, 0.f};
#pragma unroll
        for (int it = 0; it < 2; ++it)
            *(float4*)(op + lane * 4 + it * 256) = zv;
    }
}

extern "C" void kernel_launch(void* const* d_in, const int* in_sizes, int n_in,
                              void* d_out, int out_size, void* d_ws, size_t ws_size,
                              hipStream_t stream) {
    const float* video = (const float*)d_in[0];
    const float* text  = (const float*)d_in[1];
    float*    ws     = (float*)d_ws;
    unsigned* rowp   = (unsigned*)(ws + WS_ROWP);
    unsigned* colp   = (unsigned*)(ws + WS_COLP);
    int*      srcidx = (int*)(ws + WS_SRC);
    float*    out    = (float*)d_out;

    k_simmax<<<B_ * 8,          512, 0, stream>>>(video, text, rowp, colp);
    k_select<<<B_,              512, 0, stream>>>(rowp, colp, srcidx);
    k_gather<<<(B_ * 768) / 4,  256, 0, stream>>>(video, text, srcidx, out);
}